// Round 1
// baseline (4125.521 us; speedup 1.0000x reference)
//
#include <hip/hip_runtime.h>

#define NNODES 50000
#define NEDGES 800000
#define NF 96
#define NF4 (NF / 4)        // 24 float4 per row
#define EDGE_TILE 64
#define THREADS 384          // 6 waves
#define LDS_STRIDE 65        // 64 + 1 pad -> bank = (k + e) % 32, conflict-free

// ---------------------------------------------------------------------------
// Transpose the three 96x96 weight matrices: Wt[k][o] = W[o][k]
// ---------------------------------------------------------------------------
__global__ void transpose_all(const float* __restrict__ We,
                              const float* __restrict__ W1,
                              const float* __restrict__ W2,
                              float* __restrict__ WtE,
                              float* __restrict__ W1t,
                              float* __restrict__ W2t) {
    const float* A;
    float* At;
    if (blockIdx.x == 0)      { A = We; At = WtE; }
    else if (blockIdx.x == 1) { A = W1; At = W1t; }
    else                      { A = W2; At = W2t; }
    for (int i = threadIdx.x; i < NF * NF; i += blockDim.x) {
        int o = i / NF, k = i % NF;
        At[k * NF + o] = A[o * NF + k];
    }
}

// ---------------------------------------------------------------------------
// Edge kernel: ea = attr @ We^T + be; msg = relu(x[src] + ea); aggr[dst] += msg
// Block: 64 edges x 96 outputs. Lane = edge, wave = 16-output slice.
// Weights read wave-uniformly (s_load), attr tile staged transposed in LDS.
// ---------------------------------------------------------------------------
__global__ __launch_bounds__(THREADS) void edge_kernel(
    const float* __restrict__ attr, const int* __restrict__ ei,
    const float* __restrict__ x, const float* __restrict__ Wt,
    const float* __restrict__ be, float* __restrict__ aggr) {
    __shared__ float At[NF][LDS_STRIDE];

    const int t = threadIdx.x;
    const int e0 = blockIdx.x * EDGE_TILE;

    // Stage 64x96 attr tile, transposed. Coalesced float4 global reads.
    const float4* a4 = reinterpret_cast<const float4*>(attr) + (size_t)e0 * NF4;
#pragma unroll
    for (int j = 0; j < (EDGE_TILE * NF4) / THREADS; ++j) {  // 4 iters
        int f4 = t + THREADS * j;
        int e = f4 / NF4, k4 = f4 % NF4;
        float4 v = a4[f4];
        At[4 * k4 + 0][e] = v.x;
        At[4 * k4 + 1][e] = v.y;
        At[4 * k4 + 2][e] = v.z;
        At[4 * k4 + 3][e] = v.w;
    }
    __syncthreads();

    const int lane = t & 63;
    const int wv = __builtin_amdgcn_readfirstlane(t >> 6);  // wave id, uniform
    const int ob4 = wv * 4;  // float4 index of this wave's 16-output base
    const float4* Wt4 = reinterpret_cast<const float4*>(Wt);
    const float4* b4 = reinterpret_cast<const float4*>(be);

    float acc[16];
#pragma unroll
    for (int j = 0; j < 4; ++j) {
        float4 b = b4[ob4 + j];
        acc[4 * j + 0] = b.x; acc[4 * j + 1] = b.y;
        acc[4 * j + 2] = b.z; acc[4 * j + 3] = b.w;
    }

#pragma unroll 8
    for (int k = 0; k < NF; ++k) {
        float a = At[k][lane];
#pragma unroll
        for (int j = 0; j < 4; ++j) {
            float4 w = Wt4[k * NF4 + ob4 + j];  // wave-uniform -> s_load
            acc[4 * j + 0] = fmaf(a, w.x, acc[4 * j + 0]);
            acc[4 * j + 1] = fmaf(a, w.y, acc[4 * j + 1]);
            acc[4 * j + 2] = fmaf(a, w.z, acc[4 * j + 2]);
            acc[4 * j + 3] = fmaf(a, w.w, acc[4 * j + 3]);
        }
    }

    const int e = e0 + lane;
    const int s = ei[e];
    const int d = ei[NEDGES + e];
    const float4* x4 = reinterpret_cast<const float4*>(x) + (size_t)s * NF4;
    float* ag = aggr + (size_t)d * NF + wv * 16;
#pragma unroll
    for (int j = 0; j < 4; ++j) {
        float4 xv = x4[ob4 + j];
        float m0 = fmaxf(acc[4 * j + 0] + xv.x, 0.0f);
        float m1 = fmaxf(acc[4 * j + 1] + xv.y, 0.0f);
        float m2 = fmaxf(acc[4 * j + 2] + xv.z, 0.0f);
        float m3 = fmaxf(acc[4 * j + 3] + xv.w, 0.0f);
        unsafeAtomicAdd(ag + 4 * j + 0, m0);
        unsafeAtomicAdd(ag + 4 * j + 1, m1);
        unsafeAtomicAdd(ag + 4 * j + 2, m2);
        unsafeAtomicAdd(ag + 4 * j + 3, m3);
    }
}

// ---------------------------------------------------------------------------
// Node kernel: h = (1+eps)*x + aggr; h1 = relu(h @ W1^T + b1); out = h1 @ W2^T + b2
// Same skeleton: 64 nodes per block, lane = node, wave = 16-output slice.
// ---------------------------------------------------------------------------
__global__ __launch_bounds__(THREADS) void node_kernel(
    const float* __restrict__ x, const float* __restrict__ aggr,
    const float* __restrict__ epsp,
    const float* __restrict__ W1t, const float* __restrict__ b1,
    const float* __restrict__ W2t, const float* __restrict__ b2,
    float* __restrict__ out) {
    __shared__ float Ht[NF][LDS_STRIDE];
    __shared__ float H1t[NF][LDS_STRIDE];

    const int t = threadIdx.x;
    const int n0 = blockIdx.x * 64;
    const float ep = 1.0f + *epsp;

    const float4* x4 = reinterpret_cast<const float4*>(x);
    const float4* g4 = reinterpret_cast<const float4*>(aggr);
#pragma unroll
    for (int j = 0; j < 4; ++j) {
        int f4 = t + THREADS * j;
        int n = f4 / NF4, k4 = f4 % NF4;
        float4 xv = make_float4(0.f, 0.f, 0.f, 0.f);
        float4 gv = make_float4(0.f, 0.f, 0.f, 0.f);
        if (n0 + n < NNODES) {
            size_t idx = (size_t)(n0 + n) * NF4 + k4;
            xv = x4[idx];
            gv = g4[idx];
        }
        Ht[4 * k4 + 0][n] = fmaf(ep, xv.x, gv.x);
        Ht[4 * k4 + 1][n] = fmaf(ep, xv.y, gv.y);
        Ht[4 * k4 + 2][n] = fmaf(ep, xv.z, gv.z);
        Ht[4 * k4 + 3][n] = fmaf(ep, xv.w, gv.w);
    }
    __syncthreads();

    const int lane = t & 63;
    const int wv = __builtin_amdgcn_readfirstlane(t >> 6);
    const int ob4 = wv * 4;
    const float4* W1t4 = reinterpret_cast<const float4*>(W1t);
    const float4* W2t4 = reinterpret_cast<const float4*>(W2t);
    const float4* b14 = reinterpret_cast<const float4*>(b1);
    const float4* b24 = reinterpret_cast<const float4*>(b2);

    float acc[16];
#pragma unroll
    for (int j = 0; j < 4; ++j) {
        float4 b = b14[ob4 + j];
        acc[4 * j + 0] = b.x; acc[4 * j + 1] = b.y;
        acc[4 * j + 2] = b.z; acc[4 * j + 3] = b.w;
    }
#pragma unroll 8
    for (int k = 0; k < NF; ++k) {
        float a = Ht[k][lane];
#pragma unroll
        for (int j = 0; j < 4; ++j) {
            float4 w = W1t4[k * NF4 + ob4 + j];
            acc[4 * j + 0] = fmaf(a, w.x, acc[4 * j + 0]);
            acc[4 * j + 1] = fmaf(a, w.y, acc[4 * j + 1]);
            acc[4 * j + 2] = fmaf(a, w.z, acc[4 * j + 2]);
            acc[4 * j + 3] = fmaf(a, w.w, acc[4 * j + 3]);
        }
    }
    // relu -> H1t (transposed for GEMM2)
#pragma unroll
    for (int j = 0; j < 16; ++j)
        H1t[wv * 16 + j][lane] = fmaxf(acc[j], 0.0f);
    __syncthreads();

    float acc2[16];
#pragma unroll
    for (int j = 0; j < 4; ++j) {
        float4 b = b24[ob4 + j];
        acc2[4 * j + 0] = b.x; acc2[4 * j + 1] = b.y;
        acc2[4 * j + 2] = b.z; acc2[4 * j + 3] = b.w;
    }
#pragma unroll 8
    for (int k = 0; k < NF; ++k) {
        float a = H1t[k][lane];
#pragma unroll
        for (int j = 0; j < 4; ++j) {
            float4 w = W2t4[k * NF4 + ob4 + j];
            acc2[4 * j + 0] = fmaf(a, w.x, acc2[4 * j + 0]);
            acc2[4 * j + 1] = fmaf(a, w.y, acc2[4 * j + 1]);
            acc2[4 * j + 2] = fmaf(a, w.z, acc2[4 * j + 2]);
            acc2[4 * j + 3] = fmaf(a, w.w, acc2[4 * j + 3]);
        }
    }

    const int n = n0 + lane;
    if (n < NNODES) {
        float4* o4 = reinterpret_cast<float4*>(out) + (size_t)n * NF4;
#pragma unroll
        for (int j = 0; j < 4; ++j)
            o4[ob4 + j] = make_float4(acc2[4 * j + 0], acc2[4 * j + 1],
                                      acc2[4 * j + 2], acc2[4 * j + 3]);
    }
}

// ---------------------------------------------------------------------------
extern "C" void kernel_launch(void* const* d_in, const int* in_sizes, int n_in,
                              void* d_out, int out_size, void* d_ws, size_t ws_size,
                              hipStream_t stream) {
    const float* x   = (const float*)d_in[0];
    const int*   ei  = (const int*)d_in[1];
    const float* ea  = (const float*)d_in[2];
    const float* We  = (const float*)d_in[3];
    const float* be  = (const float*)d_in[4];
    const float* eps = (const float*)d_in[5];
    const float* W1  = (const float*)d_in[6];
    const float* b1  = (const float*)d_in[7];
    const float* W2  = (const float*)d_in[8];
    const float* b2  = (const float*)d_in[9];
    float* out = (float*)d_out;

    float* aggr = (float*)d_ws;                       // NNODES*NF floats
    float* WtE  = aggr + (size_t)NNODES * NF;
    float* W1t  = WtE + NF * NF;
    float* W2t  = W1t + NF * NF;

    hipMemsetAsync(aggr, 0, (size_t)NNODES * NF * sizeof(float), stream);
    transpose_all<<<3, 256, 0, stream>>>(We, W1, W2, WtE, W1t, W2t);
    edge_kernel<<<NEDGES / EDGE_TILE, THREADS, 0, stream>>>(ea, ei, x, WtE, be, aggr);
    node_kernel<<<(NNODES + 63) / 64, THREADS, 0, stream>>>(x, aggr, eps, W1t, b1,
                                                            W2t, b2, out);
}

// Round 2
// 587.630 us; speedup vs baseline: 7.0206x; 7.0206x over previous
//
#include <hip/hip_runtime.h>

#define NNODES 50000
#define NEDGES 800000
#define NF 96
#define NF4 (NF / 4)        // 24 float4 per row
#define EDGE_TILE 64
#define THREADS 384          // 6 waves
#define LDS_STRIDE 65        // 64 + 1 pad -> bank = (k + e) % 32, conflict-free

// ---------------------------------------------------------------------------
// Transpose the three 96x96 weight matrices: Wt[k][o] = W[o][k]
// ---------------------------------------------------------------------------
__global__ void transpose_all(const float* __restrict__ We,
                              const float* __restrict__ W1,
                              const float* __restrict__ W2,
                              float* __restrict__ WtE,
                              float* __restrict__ W1t,
                              float* __restrict__ W2t) {
    const float* A;
    float* At;
    if (blockIdx.x == 0)      { A = We; At = WtE; }
    else if (blockIdx.x == 1) { A = W1; At = W1t; }
    else                      { A = W2; At = W2t; }
    for (int i = threadIdx.x; i < NF * NF; i += blockDim.x) {
        int o = i / NF, k = i % NF;
        At[k * NF + o] = A[o * NF + k];
    }
}

// ---------------------------------------------------------------------------
// CSR build: histogram of dst, prefix scan, slot fill (int atomics only)
// ---------------------------------------------------------------------------
__global__ void hist_kernel(const int* __restrict__ ei, int* __restrict__ deg) {
    int e = blockIdx.x * blockDim.x + threadIdx.x;
    if (e < NEDGES) atomicAdd(&deg[ei[NEDGES + e]], 1);
}

__global__ __launch_bounds__(1024) void scan_kernel(const int* __restrict__ deg,
                                                    int* __restrict__ start,
                                                    int* __restrict__ cursor) {
    __shared__ int part[1024];
    const int t = threadIdx.x;
    const int CH = (NNODES + 1023) / 1024;  // 49
    int lo = t * CH, hi = lo + CH < NNODES ? lo + CH : NNODES;
    int s = 0;
    for (int i = lo; i < hi; ++i) s += deg[i];
    part[t] = s;
    __syncthreads();
    for (int off = 1; off < 1024; off <<= 1) {
        int v = (t >= off) ? part[t - off] : 0;
        __syncthreads();
        part[t] += v;
        __syncthreads();
    }
    int base = (t == 0) ? 0 : part[t - 1];
    for (int i = lo; i < hi; ++i) {
        start[i] = base;
        cursor[i] = base;
        base += deg[i];
    }
    if (t == 1023) start[NNODES] = part[1023];
}

__global__ void fill_kernel(const int* __restrict__ ei, int* __restrict__ cursor,
                            int* __restrict__ eidx) {
    int e = blockIdx.x * blockDim.x + threadIdx.x;
    if (e < NEDGES) {
        int p = atomicAdd(&cursor[ei[NEDGES + e]], 1);
        eidx[p] = e;
    }
}

// ---------------------------------------------------------------------------
// Edge kernel: msg[e] = relu(x[src] + attr @ We^T + be)   (coalesced write)
// Block: 64 edges x 96 outputs. Lane = edge, wave = 16-output slice.
// ---------------------------------------------------------------------------
__global__ __launch_bounds__(THREADS) void edge_kernel(
    const float* __restrict__ attr, const int* __restrict__ ei,
    const float* __restrict__ x, const float* __restrict__ Wt,
    const float* __restrict__ be, float* __restrict__ msg) {
    __shared__ float At[NF][LDS_STRIDE];

    const int t = threadIdx.x;
    const int e0 = blockIdx.x * EDGE_TILE;

    const float4* a4 = reinterpret_cast<const float4*>(attr) + (size_t)e0 * NF4;
#pragma unroll
    for (int j = 0; j < (EDGE_TILE * NF4) / THREADS; ++j) {  // 4 iters
        int f4 = t + THREADS * j;
        int e = f4 / NF4, k4 = f4 % NF4;
        float4 v = a4[f4];
        At[4 * k4 + 0][e] = v.x;
        At[4 * k4 + 1][e] = v.y;
        At[4 * k4 + 2][e] = v.z;
        At[4 * k4 + 3][e] = v.w;
    }
    __syncthreads();

    const int lane = t & 63;
    const int wv = __builtin_amdgcn_readfirstlane(t >> 6);
    const int ob4 = wv * 4;  // float4 index of this wave's 16-output base
    const float4* Wt4 = reinterpret_cast<const float4*>(Wt);
    const float4* b4 = reinterpret_cast<const float4*>(be);

    float acc[16];
#pragma unroll
    for (int j = 0; j < 4; ++j) {
        float4 b = b4[ob4 + j];
        acc[4 * j + 0] = b.x; acc[4 * j + 1] = b.y;
        acc[4 * j + 2] = b.z; acc[4 * j + 3] = b.w;
    }

#pragma unroll 8
    for (int k = 0; k < NF; ++k) {
        float a = At[k][lane];
#pragma unroll
        for (int j = 0; j < 4; ++j) {
            float4 w = Wt4[k * NF4 + ob4 + j];  // wave-uniform -> s_load
            acc[4 * j + 0] = fmaf(a, w.x, acc[4 * j + 0]);
            acc[4 * j + 1] = fmaf(a, w.y, acc[4 * j + 1]);
            acc[4 * j + 2] = fmaf(a, w.z, acc[4 * j + 2]);
            acc[4 * j + 3] = fmaf(a, w.w, acc[4 * j + 3]);
        }
    }

    const int e = e0 + lane;
    const int s = ei[e];
    const float4* x4 = reinterpret_cast<const float4*>(x) + (size_t)s * NF4;
    float4* mrow = reinterpret_cast<float4*>(msg) + (size_t)e * NF4;
#pragma unroll
    for (int j = 0; j < 4; ++j) {
        float4 xv = x4[ob4 + j];
        mrow[ob4 + j] = make_float4(fmaxf(acc[4 * j + 0] + xv.x, 0.0f),
                                    fmaxf(acc[4 * j + 1] + xv.y, 0.0f),
                                    fmaxf(acc[4 * j + 2] + xv.z, 0.0f),
                                    fmaxf(acc[4 * j + 3] + xv.w, 0.0f));
    }
}

// ---------------------------------------------------------------------------
// Gather kernel: h[n] = (1+eps)*x[n] + sum_{e: dst(e)=n} msg[e]
// 24 threads per node, one float4 per thread. No atomics.
// ---------------------------------------------------------------------------
#define GB_NODES 16  // 384 / 24
__global__ __launch_bounds__(THREADS) void gather_kernel(
    const float* __restrict__ msg, const int* __restrict__ eidx,
    const int* __restrict__ start, const float* __restrict__ x,
    const float* __restrict__ epsp, float* __restrict__ h) {
    const int t = threadIdx.x;
    const int n = blockIdx.x * GB_NODES + t / NF4;
    const int f4 = t % NF4;
    if (n >= NNODES) return;

    const float4* m4 = reinterpret_cast<const float4*>(msg);
    const float4* x4 = reinterpret_cast<const float4*>(x);
    const float ep = 1.0f + *epsp;

    float4 xv = x4[(size_t)n * NF4 + f4];
    float4 acc = make_float4(ep * xv.x, ep * xv.y, ep * xv.z, ep * xv.w);

    const int s0 = start[n], s1 = start[n + 1];
    for (int i = s0; i < s1; ++i) {
        int e = eidx[i];
        float4 v = m4[(size_t)e * NF4 + f4];
        acc.x += v.x; acc.y += v.y; acc.z += v.z; acc.w += v.w;
    }
    reinterpret_cast<float4*>(h)[(size_t)n * NF4 + f4] = acc;
}

// ---------------------------------------------------------------------------
// Node MLP: out = relu(h @ W1^T + b1) @ W2^T + b2
// ---------------------------------------------------------------------------
__global__ __launch_bounds__(THREADS) void node_kernel(
    const float* __restrict__ h,
    const float* __restrict__ W1t, const float* __restrict__ b1,
    const float* __restrict__ W2t, const float* __restrict__ b2,
    float* __restrict__ out) {
    __shared__ float Ht[NF][LDS_STRIDE];
    __shared__ float H1t[NF][LDS_STRIDE];

    const int t = threadIdx.x;
    const int n0 = blockIdx.x * 64;

    const float4* h4 = reinterpret_cast<const float4*>(h);
#pragma unroll
    for (int j = 0; j < 4; ++j) {
        int f4 = t + THREADS * j;
        int n = f4 / NF4, k4 = f4 % NF4;
        float4 v = make_float4(0.f, 0.f, 0.f, 0.f);
        if (n0 + n < NNODES) v = h4[(size_t)(n0 + n) * NF4 + k4];
        Ht[4 * k4 + 0][n] = v.x;
        Ht[4 * k4 + 1][n] = v.y;
        Ht[4 * k4 + 2][n] = v.z;
        Ht[4 * k4 + 3][n] = v.w;
    }
    __syncthreads();

    const int lane = t & 63;
    const int wv = __builtin_amdgcn_readfirstlane(t >> 6);
    const int ob4 = wv * 4;
    const float4* W1t4 = reinterpret_cast<const float4*>(W1t);
    const float4* W2t4 = reinterpret_cast<const float4*>(W2t);
    const float4* b14 = reinterpret_cast<const float4*>(b1);
    const float4* b24 = reinterpret_cast<const float4*>(b2);

    float acc[16];
#pragma unroll
    for (int j = 0; j < 4; ++j) {
        float4 b = b14[ob4 + j];
        acc[4 * j + 0] = b.x; acc[4 * j + 1] = b.y;
        acc[4 * j + 2] = b.z; acc[4 * j + 3] = b.w;
    }
#pragma unroll 8
    for (int k = 0; k < NF; ++k) {
        float a = Ht[k][lane];
#pragma unroll
        for (int j = 0; j < 4; ++j) {
            float4 w = W1t4[k * NF4 + ob4 + j];
            acc[4 * j + 0] = fmaf(a, w.x, acc[4 * j + 0]);
            acc[4 * j + 1] = fmaf(a, w.y, acc[4 * j + 1]);
            acc[4 * j + 2] = fmaf(a, w.z, acc[4 * j + 2]);
            acc[4 * j + 3] = fmaf(a, w.w, acc[4 * j + 3]);
        }
    }
#pragma unroll
    for (int j = 0; j < 16; ++j)
        H1t[wv * 16 + j][lane] = fmaxf(acc[j], 0.0f);
    __syncthreads();

    float acc2[16];
#pragma unroll
    for (int j = 0; j < 4; ++j) {
        float4 b = b24[ob4 + j];
        acc2[4 * j + 0] = b.x; acc2[4 * j + 1] = b.y;
        acc2[4 * j + 2] = b.z; acc2[4 * j + 3] = b.w;
    }
#pragma unroll 8
    for (int k = 0; k < NF; ++k) {
        float a = H1t[k][lane];
#pragma unroll
        for (int j = 0; j < 4; ++j) {
            float4 w = W2t4[k * NF4 + ob4 + j];
            acc2[4 * j + 0] = fmaf(a, w.x, acc2[4 * j + 0]);
            acc2[4 * j + 1] = fmaf(a, w.y, acc2[4 * j + 1]);
            acc2[4 * j + 2] = fmaf(a, w.z, acc2[4 * j + 2]);
            acc2[4 * j + 3] = fmaf(a, w.w, acc2[4 * j + 3]);
        }
    }

    const int n = n0 + lane;
    if (n < NNODES) {
        float4* o4 = reinterpret_cast<float4*>(out) + (size_t)n * NF4;
#pragma unroll
        for (int j = 0; j < 4; ++j)
            o4[ob4 + j] = make_float4(acc2[4 * j + 0], acc2[4 * j + 1],
                                      acc2[4 * j + 2], acc2[4 * j + 3]);
    }
}

// ---------------------------------------------------------------------------
extern "C" void kernel_launch(void* const* d_in, const int* in_sizes, int n_in,
                              void* d_out, int out_size, void* d_ws, size_t ws_size,
                              hipStream_t stream) {
    const float* x   = (const float*)d_in[0];
    const int*   ei  = (const int*)d_in[1];
    const float* ea  = (const float*)d_in[2];
    const float* We  = (const float*)d_in[3];
    const float* be  = (const float*)d_in[4];
    const float* eps = (const float*)d_in[5];
    const float* W1  = (const float*)d_in[6];
    const float* b1  = (const float*)d_in[7];
    const float* W2  = (const float*)d_in[8];
    const float* b2  = (const float*)d_in[9];
    float* out = (float*)d_out;

    // ws layout
    float* msg  = (float*)d_ws;                         // 800000*96 f  (307.2 MB)
    float* h    = msg + (size_t)NEDGES * NF;            // 50000*96 f   (19.2 MB)
    float* WtE  = h + (size_t)NNODES * NF;              // 3 x 96*96 f
    float* W1t  = WtE + NF * NF;
    float* W2t  = W1t + NF * NF;
    int* deg    = (int*)(W2t + NF * NF);                // 50000
    int* start  = deg + NNODES;                         // 50001
    int* cursor = start + NNODES + 1;                   // 50000
    int* eidx   = cursor + NNODES;                      // 800000

    hipMemsetAsync(deg, 0, NNODES * sizeof(int), stream);
    transpose_all<<<3, 256, 0, stream>>>(We, W1, W2, WtE, W1t, W2t);
    hist_kernel<<<(NEDGES + 255) / 256, 256, 0, stream>>>(ei, deg);
    scan_kernel<<<1, 1024, 0, stream>>>(deg, start, cursor);
    fill_kernel<<<(NEDGES + 255) / 256, 256, 0, stream>>>(ei, cursor, eidx);
    edge_kernel<<<NEDGES / EDGE_TILE, THREADS, 0, stream>>>(ea, ei, x, WtE, be, msg);
    gather_kernel<<<(NNODES + GB_NODES - 1) / GB_NODES, THREADS, 0, stream>>>(
        msg, eidx, start, x, eps, h);
    node_kernel<<<(NNODES + 63) / 64, THREADS, 0, stream>>>(h, W1t, b1, W2t, b2, out);
}

// Round 3
// 575.531 us; speedup vs baseline: 7.1682x; 1.0210x over previous
//
#include <hip/hip_runtime.h>

#define NNODES 50000
#define NEDGES 800000
#define NF 96
#define NF4 (NF / 4)        // 24 float4 per row
#define CHUNK 64            // edges per GEMM tile
#define NB 16               // nodes per block (50000 / 16 = 3125 exactly)
#define THREADS 384         // 6 waves
#define LDS_STRIDE 65       // 64 + 1 pad -> bank = (k + e) % 32, conflict-free

// ---------------------------------------------------------------------------
// Transpose the three 96x96 weight matrices: Wt[k][o] = W[o][k]
// ---------------------------------------------------------------------------
__global__ void transpose_all(const float* __restrict__ We,
                              const float* __restrict__ W1,
                              const float* __restrict__ W2,
                              float* __restrict__ WtE,
                              float* __restrict__ W1t,
                              float* __restrict__ W2t) {
    const float* A;
    float* At;
    if (blockIdx.x == 0)      { A = We; At = WtE; }
    else if (blockIdx.x == 1) { A = W1; At = W1t; }
    else                      { A = W2; At = W2t; }
    for (int i = threadIdx.x; i < NF * NF; i += blockDim.x) {
        int o = i / NF, k = i % NF;
        At[k * NF + o] = A[o * NF + k];
    }
}

// ---------------------------------------------------------------------------
// CSR build: histogram of dst, prefix scan, slot fill (int atomics only)
// ---------------------------------------------------------------------------
__global__ void hist_kernel(const int* __restrict__ ei, int* __restrict__ deg) {
    int e = blockIdx.x * blockDim.x + threadIdx.x;
    if (e < NEDGES) atomicAdd(&deg[ei[NEDGES + e]], 1);
}

__global__ __launch_bounds__(1024) void scan_kernel(const int* __restrict__ deg,
                                                    int* __restrict__ start,
                                                    int* __restrict__ cursor) {
    __shared__ int part[1024];
    const int t = threadIdx.x;
    const int CH = (NNODES + 1023) / 1024;  // 49
    int lo = t * CH, hi = lo + CH < NNODES ? lo + CH : NNODES;
    int s = 0;
    for (int i = lo; i < hi; ++i) s += deg[i];
    part[t] = s;
    __syncthreads();
    for (int off = 1; off < 1024; off <<= 1) {
        int v = (t >= off) ? part[t - off] : 0;
        __syncthreads();
        part[t] += v;
        __syncthreads();
    }
    int base = (t == 0) ? 0 : part[t - 1];
    for (int i = lo; i < hi; ++i) {
        start[i] = base;
        cursor[i] = base;
        base += deg[i];
    }
    if (t == 1023) start[NNODES] = part[1023];
}

// fill: eidx[p] = edge id, srcs[p] = src node (avoids double indirection later)
__global__ void fill_kernel(const int* __restrict__ ei, int* __restrict__ cursor,
                            int* __restrict__ eidx, int* __restrict__ srcs) {
    int e = blockIdx.x * blockDim.x + threadIdx.x;
    if (e < NEDGES) {
        int p = atomicAdd(&cursor[ei[NEDGES + e]], 1);
        eidx[p] = e;
        srcs[p] = ei[e];
    }
}

// ---------------------------------------------------------------------------
// Fused edge-GEMM + segment-sum kernel.
// Block owns NB=16 nodes => contiguous CSR slot range [s0, s1).
// Per 64-edge chunk:
//   1. stage attr rows (gathered via eidx) transposed into LDS B
//   2. GEMM: lane = edge, wave = 16-output slice, acc[16] in regs
//   3. epilogue: + x[src], ReLU, write message tile back into B (as msgT)
//   4. fixed-owner threads (4 (node,feature) cells each) accumulate their
//      CSR segment from B into register accumulators.   No float atomics.
// ---------------------------------------------------------------------------
__global__ __launch_bounds__(THREADS) void fused_edge_aggr(
    const float* __restrict__ attr, const int* __restrict__ eidx,
    const int* __restrict__ srcs, const int* __restrict__ start,
    const float* __restrict__ x, const float* __restrict__ Wt,
    const float* __restrict__ be, const float* __restrict__ epsp,
    float* __restrict__ h) {
    __shared__ float B[NF][LDS_STRIDE];   // reused: attr^T staging, then msg^T
    __shared__ int sstart[NB + 1];

    const int t = threadIdx.x;
    const int n0 = blockIdx.x * NB;
    if (t <= NB) sstart[t] = start[n0 + t];
    __syncthreads();
    const int s0 = sstart[0], s1 = sstart[NB];

    const int lane = t & 63;
    const int wv = __builtin_amdgcn_readfirstlane(t >> 6);
    const int ob4 = wv * 4;  // float4 index of this wave's 16-output base
    const float4* Wt4 = reinterpret_cast<const float4*>(Wt);
    const float4* a4 = reinterpret_cast<const float4*>(attr);
    const float4* x4 = reinterpret_cast<const float4*>(x);

    float bias[16];
    {
        const float4* b4 = reinterpret_cast<const float4*>(be);
#pragma unroll
        for (int j = 0; j < 4; ++j) {
            float4 b = b4[ob4 + j];
            bias[4 * j + 0] = b.x; bias[4 * j + 1] = b.y;
            bias[4 * j + 2] = b.z; bias[4 * j + 3] = b.w;
        }
    }

    // register accumulators: thread owns items t, t+384, t+768, t+1152
    // item -> (node n = item/96, feature f = item%96)
    float racc[4] = {0.f, 0.f, 0.f, 0.f};

    for (int cl = s0; cl < s1; cl += CHUNK) {
        // ---- 1. stage attr tile (transposed) ----
#pragma unroll
        for (int p = 0; p < 4; ++p) {
            int idx = t + THREADS * p;
            int i = idx / NF4, k4 = idx % NF4;
            int slot = cl + i;
            float4 v = make_float4(0.f, 0.f, 0.f, 0.f);
            if (slot < s1) {
                int e = eidx[slot];
                v = a4[(size_t)e * NF4 + k4];
            }
            B[4 * k4 + 0][i] = v.x;
            B[4 * k4 + 1][i] = v.y;
            B[4 * k4 + 2][i] = v.z;
            B[4 * k4 + 3][i] = v.w;
        }
        __syncthreads();

        // ---- 2. GEMM ----
        float acc[16];
#pragma unroll
        for (int j = 0; j < 16; ++j) acc[j] = bias[j];
#pragma unroll 8
        for (int k = 0; k < NF; ++k) {
            float a = B[k][lane];
#pragma unroll
            for (int j = 0; j < 4; ++j) {
                float4 w = Wt4[k * NF4 + ob4 + j];  // wave-uniform -> s_load
                acc[4 * j + 0] = fmaf(a, w.x, acc[4 * j + 0]);
                acc[4 * j + 1] = fmaf(a, w.y, acc[4 * j + 1]);
                acc[4 * j + 2] = fmaf(a, w.z, acc[4 * j + 2]);
                acc[4 * j + 3] = fmaf(a, w.w, acc[4 * j + 3]);
            }
        }
        __syncthreads();  // all waves done reading B before overwrite

        // ---- 3. + x[src], ReLU, write msg tile into B ----
        {
            int slot = cl + lane;
            bool valid = slot < s1;
            int src = valid ? srcs[slot] : 0;
#pragma unroll
            for (int j = 0; j < 4; ++j) {
                float4 xv = x4[(size_t)src * NF4 + ob4 + j];
                B[wv * 16 + 4 * j + 0][lane] = fmaxf(acc[4 * j + 0] + xv.x, 0.f);
                B[wv * 16 + 4 * j + 1][lane] = fmaxf(acc[4 * j + 1] + xv.y, 0.f);
                B[wv * 16 + 4 * j + 2][lane] = fmaxf(acc[4 * j + 2] + xv.z, 0.f);
                B[wv * 16 + 4 * j + 3][lane] = fmaxf(acc[4 * j + 3] + xv.w, 0.f);
            }
        }
        __syncthreads();

        // ---- 4. segmented accumulate into register cells ----
#pragma unroll
        for (int r = 0; r < 4; ++r) {
            int item = t + THREADS * r;
            int n = item / NF, f = item % NF;
            int segLo = sstart[n] > cl ? sstart[n] : cl;
            int segHi = sstart[n + 1] < cl + CHUNK ? sstart[n + 1] : cl + CHUNK;
            float s = racc[r];
            for (int i = segLo - cl; i < segHi - cl; ++i) s += B[f][i];
            racc[r] = s;
        }
        __syncthreads();  // done reading B before next chunk's staging
    }

    // ---- write h = aggr + (1+eps)*x ----
    const float ep = 1.0f + *epsp;
#pragma unroll
    for (int r = 0; r < 4; ++r) {
        int item = t + THREADS * r;
        int n = n0 + item / NF, f = item % NF;
        h[(size_t)n * NF + f] = fmaf(ep, x[(size_t)n * NF + f], racc[r]);
    }
}

// ---------------------------------------------------------------------------
// Node MLP: out = relu(h @ W1^T + b1) @ W2^T + b2
// ---------------------------------------------------------------------------
__global__ __launch_bounds__(THREADS) void node_kernel(
    const float* __restrict__ h,
    const float* __restrict__ W1t, const float* __restrict__ b1,
    const float* __restrict__ W2t, const float* __restrict__ b2,
    float* __restrict__ out) {
    __shared__ float Ht[NF][LDS_STRIDE];
    __shared__ float H1t[NF][LDS_STRIDE];

    const int t = threadIdx.x;
    const int n0 = blockIdx.x * 64;

    const float4* h4 = reinterpret_cast<const float4*>(h);
#pragma unroll
    for (int j = 0; j < 4; ++j) {
        int f4 = t + THREADS * j;
        int n = f4 / NF4, k4 = f4 % NF4;
        float4 v = make_float4(0.f, 0.f, 0.f, 0.f);
        if (n0 + n < NNODES) v = h4[(size_t)(n0 + n) * NF4 + k4];
        Ht[4 * k4 + 0][n] = v.x;
        Ht[4 * k4 + 1][n] = v.y;
        Ht[4 * k4 + 2][n] = v.z;
        Ht[4 * k4 + 3][n] = v.w;
    }
    __syncthreads();

    const int lane = t & 63;
    const int wv = __builtin_amdgcn_readfirstlane(t >> 6);
    const int ob4 = wv * 4;
    const float4* W1t4 = reinterpret_cast<const float4*>(W1t);
    const float4* W2t4 = reinterpret_cast<const float4*>(W2t);
    const float4* b14 = reinterpret_cast<const float4*>(b1);
    const float4* b24 = reinterpret_cast<const float4*>(b2);

    float acc[16];
#pragma unroll
    for (int j = 0; j < 4; ++j) {
        float4 b = b14[ob4 + j];
        acc[4 * j + 0] = b.x; acc[4 * j + 1] = b.y;
        acc[4 * j + 2] = b.z; acc[4 * j + 3] = b.w;
    }
#pragma unroll 8
    for (int k = 0; k < NF; ++k) {
        float a = Ht[k][lane];
#pragma unroll
        for (int j = 0; j < 4; ++j) {
            float4 w = W1t4[k * NF4 + ob4 + j];
            acc[4 * j + 0] = fmaf(a, w.x, acc[4 * j + 0]);
            acc[4 * j + 1] = fmaf(a, w.y, acc[4 * j + 1]);
            acc[4 * j + 2] = fmaf(a, w.z, acc[4 * j + 2]);
            acc[4 * j + 3] = fmaf(a, w.w, acc[4 * j + 3]);
        }
    }
#pragma unroll
    for (int j = 0; j < 16; ++j)
        H1t[wv * 16 + j][lane] = fmaxf(acc[j], 0.0f);
    __syncthreads();

    float acc2[16];
#pragma unroll
    for (int j = 0; j < 4; ++j) {
        float4 b = b24[ob4 + j];
        acc2[4 * j + 0] = b.x; acc2[4 * j + 1] = b.y;
        acc2[4 * j + 2] = b.z; acc2[4 * j + 3] = b.w;
    }
#pragma unroll 8
    for (int k = 0; k < NF; ++k) {
        float a = H1t[k][lane];
#pragma unroll
        for (int j = 0; j < 4; ++j) {
            float4 w = W2t4[k * NF4 + ob4 + j];
            acc2[4 * j + 0] = fmaf(a, w.x, acc2[4 * j + 0]);
            acc2[4 * j + 1] = fmaf(a, w.y, acc2[4 * j + 1]);
            acc2[4 * j + 2] = fmaf(a, w.z, acc2[4 * j + 2]);
            acc2[4 * j + 3] = fmaf(a, w.w, acc2[4 * j + 3]);
        }
    }

    const int n = n0 + lane;
    if (n < NNODES) {
        float4* o4 = reinterpret_cast<float4*>(out) + (size_t)n * NF4;
#pragma unroll
        for (int j = 0; j < 4; ++j)
            o4[ob4 + j] = make_float4(acc2[4 * j + 0], acc2[4 * j + 1],
                                      acc2[4 * j + 2], acc2[4 * j + 3]);
    }
}

// ---------------------------------------------------------------------------
extern "C" void kernel_launch(void* const* d_in, const int* in_sizes, int n_in,
                              void* d_out, int out_size, void* d_ws, size_t ws_size,
                              hipStream_t stream) {
    const float* x   = (const float*)d_in[0];
    const int*   ei  = (const int*)d_in[1];
    const float* ea  = (const float*)d_in[2];
    const float* We  = (const float*)d_in[3];
    const float* be  = (const float*)d_in[4];
    const float* eps = (const float*)d_in[5];
    const float* W1  = (const float*)d_in[6];
    const float* b1  = (const float*)d_in[7];
    const float* W2  = (const float*)d_in[8];
    const float* b2  = (const float*)d_in[9];
    float* out = (float*)d_out;

    // ws layout (no msg buffer anymore)
    float* h    = (float*)d_ws;                         // 50000*96 f (19.2 MB)
    float* WtE  = h + (size_t)NNODES * NF;              // 3 x 96*96 f
    float* W1t  = WtE + NF * NF;
    float* W2t  = W1t + NF * NF;
    int* deg    = (int*)(W2t + NF * NF);                // 50000
    int* start  = deg + NNODES;                         // 50001
    int* cursor = start + NNODES + 1;                   // 50000
    int* eidx   = cursor + NNODES;                      // 800000
    int* srcs   = eidx + NEDGES;                        // 800000

    hipMemsetAsync(deg, 0, NNODES * sizeof(int), stream);
    transpose_all<<<3, 256, 0, stream>>>(We, W1, W2, WtE, W1t, W2t);
    hist_kernel<<<(NEDGES + 255) / 256, 256, 0, stream>>>(ei, deg);
    scan_kernel<<<1, 1024, 0, stream>>>(deg, start, cursor);
    fill_kernel<<<(NEDGES + 255) / 256, 256, 0, stream>>>(ei, cursor, eidx, srcs);
    fused_edge_aggr<<<NNODES / NB, THREADS, 0, stream>>>(ea, eidx, srcs, start, x,
                                                         WtE, be, eps, h);
    node_kernel<<<(NNODES + 63) / 64, THREADS, 0, stream>>>(h, W1t, b1, W2t, b2, out);
}